// Round 4
// baseline (8642.466 us; speedup 1.0000x reference)
//
#include <hip/hip_runtime.h>
#include <hip/hip_bf16.h>
#include <math.h>

// Problem constants
#define B_  16
#define NE_ 512
#define NIN_ 1024
#define NOUT_ 1024
#define H_ 16
#define HD_ 64
#define ROWS_ (B_ * NE_)          // 8192
#define HHD_ (H_ * HD_)           // 1024

// ---------------------------------------------------------------------------
// LayerNorm (PyTorch-style: unbiased std (ddof=1), eps added to std)
// ---------------------------------------------------------------------------
__global__ __launch_bounds__(256) void layernorm_kernel(
    const float* __restrict__ in, const float* __restrict__ alpha,
    const float* __restrict__ beta, float* __restrict__ out) {
  const int row = blockIdx.x;
  const int t = threadIdx.x;
  const float4 v = *reinterpret_cast<const float4*>(&in[(size_t)row * 1024 + t * 4]);
  float s = v.x + v.y + v.z + v.w;
  float ss = v.x * v.x + v.y * v.y + v.z * v.z + v.w * v.w;
  #pragma unroll
  for (int off = 32; off >= 1; off >>= 1) {
    s += __shfl_xor(s, off);
    ss += __shfl_xor(ss, off);
  }
  __shared__ float red[8];
  const int w = t >> 6, lane = t & 63;
  if (lane == 0) { red[w] = s; red[4 + w] = ss; }
  __syncthreads();
  s = red[0] + red[1] + red[2] + red[3];
  ss = red[4] + red[5] + red[6] + red[7];
  const float mean = s * (1.0f / 1024.0f);
  float var = (ss - 1024.0f * mean * mean) * (1.0f / 1023.0f);
  var = fmaxf(var, 0.0f);
  const float inv = 1.0f / (sqrtf(var) + 1e-6f);
  const float4 a = *reinterpret_cast<const float4*>(&alpha[t * 4]);
  const float4 bt = *reinterpret_cast<const float4*>(&beta[t * 4]);
  float4 o;
  o.x = a.x * (v.x - mean) * inv + bt.x;
  o.y = a.y * (v.y - mean) * inv + bt.y;
  o.z = a.z * (v.z - mean) * inv + bt.z;
  o.w = a.w * (v.w - mean) * inv + bt.w;
  *reinterpret_cast<float4*>(&out[(size_t)row * 1024 + t * 4]) = o;
}

// ---------------------------------------------------------------------------
// fp32 NT GEMM: C[M,N] = A[M,K] * W[N,K]^T + bias[N]  (unchanged from r3)
// ---------------------------------------------------------------------------
#define BT 128   // tile
#define BKK 16   // k-step
#define LDT 132  // padded LDS stride (floats)

__global__ __launch_bounds__(256) void gemm_nt_bias(
    const float* __restrict__ A, const float* __restrict__ W,
    const float* __restrict__ bias, float* __restrict__ C) {
  __shared__ float As[BKK][LDT];
  __shared__ float Ws[BKK][LDT];
  const int tid = threadIdx.x;
  const int ty = tid >> 4;   // 0..15
  const int tx = tid & 15;   // 0..15
  const int rb = blockIdx.y * BT;
  const int cb = blockIdx.x * BT;
  const int K = 1024, N = 1024;

  float acc[8][8] = {};

  for (int kt = 0; kt < K; kt += BKK) {
    #pragma unroll
    for (int i = 0; i < 2; ++i) {
      const int L = tid + i * 256;
      const int row = L >> 2;
      const int c4 = L & 3;
      const float4 av = *reinterpret_cast<const float4*>(
          &A[(size_t)(rb + row) * K + kt + c4 * 4]);
      As[c4 * 4 + 0][row] = av.x; As[c4 * 4 + 1][row] = av.y;
      As[c4 * 4 + 2][row] = av.z; As[c4 * 4 + 3][row] = av.w;
      const float4 wv = *reinterpret_cast<const float4*>(
          &W[(size_t)(cb + row) * K + kt + c4 * 4]);
      Ws[c4 * 4 + 0][row] = wv.x; Ws[c4 * 4 + 1][row] = wv.y;
      Ws[c4 * 4 + 2][row] = wv.z; Ws[c4 * 4 + 3][row] = wv.w;
    }
    __syncthreads();
    #pragma unroll
    for (int k = 0; k < BKK; ++k) {
      float ar[8], br[8];
      *reinterpret_cast<float4*>(&ar[0]) =
          *reinterpret_cast<const float4*>(&As[k][ty * 4]);
      *reinterpret_cast<float4*>(&ar[4]) =
          *reinterpret_cast<const float4*>(&As[k][64 + ty * 4]);
      *reinterpret_cast<float4*>(&br[0]) =
          *reinterpret_cast<const float4*>(&Ws[k][tx * 4]);
      *reinterpret_cast<float4*>(&br[4]) =
          *reinterpret_cast<const float4*>(&Ws[k][64 + tx * 4]);
      #pragma unroll
      for (int i = 0; i < 8; ++i)
        #pragma unroll
        for (int j = 0; j < 8; ++j)
          acc[i][j] += ar[i] * br[j];
    }
    __syncthreads();
  }

  const float4 bl = *reinterpret_cast<const float4*>(&bias[cb + tx * 4]);
  const float4 bh = *reinterpret_cast<const float4*>(&bias[cb + 64 + tx * 4]);
  #pragma unroll
  for (int i = 0; i < 8; ++i) {
    const int row = rb + (i < 4 ? ty * 4 + i : 64 + ty * 4 + (i - 4));
    float4 o0, o1;
    o0.x = acc[i][0] + bl.x; o0.y = acc[i][1] + bl.y;
    o0.z = acc[i][2] + bl.z; o0.w = acc[i][3] + bl.w;
    o1.x = acc[i][4] + bh.x; o1.y = acc[i][5] + bh.y;
    o1.z = acc[i][6] + bh.z; o1.w = acc[i][7] + bh.w;
    *reinterpret_cast<float4*>(&C[(size_t)row * N + cb + tx * 4]) = o0;
    *reinterpret_cast<float4*>(&C[(size_t)row * N + cb + 64 + tx * 4]) = o1;
  }
}

// ---------------------------------------------------------------------------
// Attention v2: scores in registers, 34.8 KB LDS (4 blocks/CU), shuffle softmax.
// Per block (b,h,qt): 32 q-rows. Thread (ty,tx): rows ty*2+{0,1},
// k-cols tx*4+{0..3} in each of 8 k-chunks -> float4 acc[2][8] (64 VGPR).
// XCD swizzle: 16 q-tiles of one (b,h) land on one XCD (K/V L2 reuse).
// mask is int32 on device.
// ---------------------------------------------------------------------------
#define KLD 68   // padded LDS stride for K/V chunk (floats)

__global__ __launch_bounds__(256) void attn_kernel(
    const float* __restrict__ Qg, const float* __restrict__ Kg,
    const float* __restrict__ Vg, const int* __restrict__ mask,
    float* __restrict__ e_out, float* __restrict__ attn_out) {
  // XCD-aware swizzle: lin -> virt so virt is contiguous per XCD (4096%8==0)
  const int lin = blockIdx.x;                  // 0..4095
  const int virt = (lin & 7) * 512 + (lin >> 3);
  const int qt = virt & 15;
  const int h  = (virt >> 4) & 15;
  const int b  = virt >> 8;
  const int q0 = qt * 32;

  __shared__ float Qs[64][34];    // [d][q] transposed Q tile (8.7 KB)
  __shared__ float KVs[64][KLD];  // QK: [d][k] chunk; PV: [k][d] chunk (17.4 KB)
  __shared__ float es[32][KLD];   // per-chunk normalized e (8.7 KB)

  const int tid = threadIdx.x;
  const int ty = tid >> 4, tx = tid & 15;

  // stage Q tile transposed -> Qs[d][q] (writes: 16 distinct banks, free)
  #pragma unroll
  for (int i = 0; i < 2; ++i) {
    const int L = tid + i * 256;   // 512 float4
    const int q = L >> 4;
    const int dc = L & 15;
    const float4 v = *reinterpret_cast<const float4*>(
        &Qg[(size_t)(b * NE_ + q0 + q) * HHD_ + h * HD_ + dc * 4]);
    Qs[dc * 4 + 0][q] = v.x; Qs[dc * 4 + 1][q] = v.y;
    Qs[dc * 4 + 2][q] = v.z; Qs[dc * 4 + 3][q] = v.w;
  }

  float4 acc[2][8];
  #pragma unroll
  for (int i = 0; i < 2; ++i)
    #pragma unroll
    for (int kt = 0; kt < 8; ++kt) acc[i][kt] = float4{0.f, 0.f, 0.f, 0.f};

  // ---- QK^T: 8 chunks of 64 k ----
  #pragma unroll
  for (int kt = 0; kt < 8; ++kt) {
    __syncthreads();
    #pragma unroll
    for (int i = 0; i < 4; ++i) {
      const int L = tid + i * 256;   // 1024 float4
      const int kl = L >> 4;
      const int dc = L & 15;
      const float4 v = *reinterpret_cast<const float4*>(
          &Kg[(size_t)(b * NE_ + kt * 64 + kl) * HHD_ + h * HD_ + dc * 4]);
      KVs[dc * 4 + 0][kl] = v.x; KVs[dc * 4 + 1][kl] = v.y;
      KVs[dc * 4 + 2][kl] = v.z; KVs[dc * 4 + 3][kl] = v.w;
    }
    __syncthreads();
    #pragma unroll
    for (int d = 0; d < 64; ++d) {
      const float2 qv = *reinterpret_cast<const float2*>(&Qs[d][ty * 2]);
      const float4 kv = *reinterpret_cast<const float4*>(&KVs[d][tx * 4]);
      acc[0][kt].x += qv.x * kv.x; acc[0][kt].y += qv.x * kv.y;
      acc[0][kt].z += qv.x * kv.z; acc[0][kt].w += qv.x * kv.w;
      acc[1][kt].x += qv.y * kv.x; acc[1][kt].y += qv.y * kv.y;
      acc[1][kt].z += qv.y * kv.z; acc[1][kt].w += qv.y * kv.w;
    }
  }

  // ---- mask + scale + softmax (shuffle over the 16-lane tx-group) ----
  float m[2] = {-INFINITY, -INFINITY};
  #pragma unroll
  for (int i = 0; i < 2; ++i) {
    #pragma unroll
    for (int kt = 0; kt < 8; ++kt) {
      const int4 mv = *reinterpret_cast<const int4*>(
          &mask[(size_t)(b * NE_ + q0 + ty * 2 + i) * NE_ + kt * 64 + tx * 4]);
      float4& a = acc[i][kt];
      a.x = mv.x ? -INFINITY : a.x * 0.125f;
      a.y = mv.y ? -INFINITY : a.y * 0.125f;
      a.z = mv.z ? -INFINITY : a.z * 0.125f;
      a.w = mv.w ? -INFINITY : a.w * 0.125f;
      m[i] = fmaxf(m[i], fmaxf(fmaxf(a.x, a.y), fmaxf(a.z, a.w)));
    }
    #pragma unroll
    for (int off = 8; off >= 1; off >>= 1) m[i] = fmaxf(m[i], __shfl_xor(m[i], off));
  }
  float sum[2] = {0.f, 0.f};
  #pragma unroll
  for (int i = 0; i < 2; ++i) {
    #pragma unroll
    for (int kt = 0; kt < 8; ++kt) {
      float4& a = acc[i][kt];
      a.x = __expf(a.x - m[i]); a.y = __expf(a.y - m[i]);
      a.z = __expf(a.z - m[i]); a.w = __expf(a.w - m[i]);
      sum[i] += a.x + a.y + a.z + a.w;
    }
    #pragma unroll
    for (int off = 8; off >= 1; off >>= 1) sum[i] += __shfl_xor(sum[i], off);
    const float inv = 1.0f / sum[i];
    #pragma unroll
    for (int kt = 0; kt < 8; ++kt) {
      float4& a = acc[i][kt];
      a.x *= inv; a.y *= inv; a.z *= inv; a.w *= inv;
      *reinterpret_cast<float4*>(
          &e_out[(size_t)((b * H_ + h) * NE_ + q0 + ty * 2 + i) * NE_ +
                 kt * 64 + tx * 4]) = a;
    }
  }

  // ---- PV: per chunk, stage e (from regs) + V tile, accumulate out ----
  float4 o[2] = {float4{0.f, 0.f, 0.f, 0.f}, float4{0.f, 0.f, 0.f, 0.f}};
  #pragma unroll
  for (int kt = 0; kt < 8; ++kt) {
    __syncthreads();
    #pragma unroll
    for (int i = 0; i < 2; ++i)
      *reinterpret_cast<float4*>(&es[ty * 2 + i][tx * 4]) = acc[i][kt];
    #pragma unroll
    for (int i = 0; i < 4; ++i) {
      const int L = tid + i * 256;
      const int kl = L >> 4;
      const int dc = L & 15;
      const float4 v = *reinterpret_cast<const float4*>(
          &Vg[(size_t)(b * NE_ + kt * 64 + kl) * HHD_ + h * HD_ + dc * 4]);
      *reinterpret_cast<float4*>(&KVs[kl][dc * 4]) = v;
    }
    __syncthreads();
    #pragma unroll
    for (int k2 = 0; k2 < 64; ++k2) {
      const float4 vv = *reinterpret_cast<const float4*>(&KVs[k2][tx * 4]);
      const float e0 = es[ty * 2 + 0][k2];
      const float e1 = es[ty * 2 + 1][k2];
      o[0].x += e0 * vv.x; o[0].y += e0 * vv.y;
      o[0].z += e0 * vv.z; o[0].w += e0 * vv.w;
      o[1].x += e1 * vv.x; o[1].y += e1 * vv.y;
      o[1].z += e1 * vv.z; o[1].w += e1 * vv.w;
    }
  }
  #pragma unroll
  for (int i = 0; i < 2; ++i) {
    *reinterpret_cast<float4*>(
        &attn_out[(size_t)(b * NE_ + q0 + ty * 2 + i) * HHD_ + h * HD_ +
                  tx * 4]) = o[i];
  }
}

// ---------------------------------------------------------------------------
extern "C" void kernel_launch(void* const* d_in, const int* in_sizes, int n_in,
                              void* d_out, int out_size, void* d_ws, size_t ws_size,
                              hipStream_t stream) {
  const float* events = (const float*)d_in[0];
  const int* mask = (const int*)d_in[1];            // bool -> int32 on device
  const float* n1a = (const float*)d_in[2];
  const float* n1b = (const float*)d_in[3];
  const float* WQw = (const float*)d_in[4];
  const float* WQb = (const float*)d_in[5];
  const float* WKw = (const float*)d_in[6];
  const float* WKb = (const float*)d_in[7];
  const float* WVw = (const float*)d_in[8];
  const float* WVb = (const float*)d_in[9];
  const float* WOw = (const float*)d_in[10];
  const float* WOb = (const float*)d_in[11];
  const float* n2a = (const float*)d_in[12];
  const float* n2b = (const float*)d_in[13];

  float* out = (float*)d_out;                       // [16,512,1024]
  float* e_out = out + (size_t)ROWS_ * NOUT_;       // [16,16,512,512]

  const size_t MAT = (size_t)ROWS_ * HHD_;          // 8M floats = 32 MB
  float* xn = (float*)d_ws;        // x_norm, later reused as attn concat out
  float* Qb = xn + MAT;            // Q, later reused as WO output
  float* Kb = Qb + MAT;
  float* Vb = Kb + MAT;
  float* attn = xn;
  float* wo_out = Qb;

  // 1) layernorm1
  layernorm_kernel<<<ROWS_, 256, 0, stream>>>(events, n1a, n1b, xn);

  // 2) Q/K/V projections
  dim3 gg(HHD_ / BT, ROWS_ / BT);  // (8, 64)
  gemm_nt_bias<<<gg, 256, 0, stream>>>(xn, WQw, WQb, Qb);
  gemm_nt_bias<<<gg, 256, 0, stream>>>(xn, WKw, WKb, Kb);
  gemm_nt_bias<<<gg, 256, 0, stream>>>(xn, WVw, WVb, Vb);

  // 3) attention (+ e output), XCD-swizzled 1-D grid
  attn_kernel<<<B_ * H_ * (NE_ / 32), 256, 0, stream>>>(Qb, Kb, Vb, mask,
                                                        e_out, attn);

  // 4) output projection
  gemm_nt_bias<<<gg, 256, 0, stream>>>(attn, WOw, WOb, wo_out);

  // 5) layernorm2
  layernorm_kernel<<<ROWS_, 256, 0, stream>>>(wo_out, n2a, n2b, out);
}

// Round 5
// 7494.371 us; speedup vs baseline: 1.1532x; 1.1532x over previous
//
#include <hip/hip_runtime.h>
#include <hip/hip_bf16.h>
#include <math.h>

// Problem constants
#define B_  16
#define NE_ 512
#define NIN_ 1024
#define NOUT_ 1024
#define H_ 16
#define HD_ 64
#define ROWS_ (B_ * NE_)          // 8192
#define HHD_ (H_ * HD_)           // 1024

// ---------------------------------------------------------------------------
// LayerNorm (PyTorch-style: unbiased std (ddof=1), eps added to std)
// ---------------------------------------------------------------------------
__global__ __launch_bounds__(256) void layernorm_kernel(
    const float* __restrict__ in, const float* __restrict__ alpha,
    const float* __restrict__ beta, float* __restrict__ out) {
  const int row = blockIdx.x;
  const int t = threadIdx.x;
  const float4 v = *reinterpret_cast<const float4*>(&in[(size_t)row * 1024 + t * 4]);
  float s = v.x + v.y + v.z + v.w;
  float ss = v.x * v.x + v.y * v.y + v.z * v.z + v.w * v.w;
  #pragma unroll
  for (int off = 32; off >= 1; off >>= 1) {
    s += __shfl_xor(s, off);
    ss += __shfl_xor(ss, off);
  }
  __shared__ float red[8];
  const int w = t >> 6, lane = t & 63;
  if (lane == 0) { red[w] = s; red[4 + w] = ss; }
  __syncthreads();
  s = red[0] + red[1] + red[2] + red[3];
  ss = red[4] + red[5] + red[6] + red[7];
  const float mean = s * (1.0f / 1024.0f);
  float var = (ss - 1024.0f * mean * mean) * (1.0f / 1023.0f);
  var = fmaxf(var, 0.0f);
  const float inv = 1.0f / (sqrtf(var) + 1e-6f);
  const float4 a = *reinterpret_cast<const float4*>(&alpha[t * 4]);
  const float4 bt = *reinterpret_cast<const float4*>(&beta[t * 4]);
  float4 o;
  o.x = a.x * (v.x - mean) * inv + bt.x;
  o.y = a.y * (v.y - mean) * inv + bt.y;
  o.z = a.z * (v.z - mean) * inv + bt.z;
  o.w = a.w * (v.w - mean) * inv + bt.w;
  *reinterpret_cast<float4*>(&out[(size_t)row * 1024 + t * 4]) = o;
}

// ---------------------------------------------------------------------------
// fp32 NT GEMM: C[M,N] = A[M,K] * W[N,K]^T + bias[N]  (unchanged)
// ---------------------------------------------------------------------------
#define BT 128   // tile
#define BKK 16   // k-step
#define LDT 132  // padded LDS stride (floats)

__global__ __launch_bounds__(256) void gemm_nt_bias(
    const float* __restrict__ A, const float* __restrict__ W,
    const float* __restrict__ bias, float* __restrict__ C) {
  __shared__ float As[BKK][LDT];
  __shared__ float Ws[BKK][LDT];
  const int tid = threadIdx.x;
  const int ty = tid >> 4;   // 0..15
  const int tx = tid & 15;   // 0..15
  const int rb = blockIdx.y * BT;
  const int cb = blockIdx.x * BT;
  const int K = 1024, N = 1024;

  float acc[8][8] = {};

  for (int kt = 0; kt < K; kt += BKK) {
    #pragma unroll
    for (int i = 0; i < 2; ++i) {
      const int L = tid + i * 256;
      const int row = L >> 2;
      const int c4 = L & 3;
      const float4 av = *reinterpret_cast<const float4*>(
          &A[(size_t)(rb + row) * K + kt + c4 * 4]);
      As[c4 * 4 + 0][row] = av.x; As[c4 * 4 + 1][row] = av.y;
      As[c4 * 4 + 2][row] = av.z; As[c4 * 4 + 3][row] = av.w;
      const float4 wv = *reinterpret_cast<const float4*>(
          &W[(size_t)(cb + row) * K + kt + c4 * 4]);
      Ws[c4 * 4 + 0][row] = wv.x; Ws[c4 * 4 + 1][row] = wv.y;
      Ws[c4 * 4 + 2][row] = wv.z; Ws[c4 * 4 + 3][row] = wv.w;
    }
    __syncthreads();
    #pragma unroll
    for (int k = 0; k < BKK; ++k) {
      float ar[8], br[8];
      *reinterpret_cast<float4*>(&ar[0]) =
          *reinterpret_cast<const float4*>(&As[k][ty * 4]);
      *reinterpret_cast<float4*>(&ar[4]) =
          *reinterpret_cast<const float4*>(&As[k][64 + ty * 4]);
      *reinterpret_cast<float4*>(&br[0]) =
          *reinterpret_cast<const float4*>(&Ws[k][tx * 4]);
      *reinterpret_cast<float4*>(&br[4]) =
          *reinterpret_cast<const float4*>(&Ws[k][64 + tx * 4]);
      #pragma unroll
      for (int i = 0; i < 8; ++i)
        #pragma unroll
        for (int j = 0; j < 8; ++j)
          acc[i][j] += ar[i] * br[j];
    }
    __syncthreads();
  }

  const float4 bl = *reinterpret_cast<const float4*>(&bias[cb + tx * 4]);
  const float4 bh = *reinterpret_cast<const float4*>(&bias[cb + 64 + tx * 4]);
  #pragma unroll
  for (int i = 0; i < 8; ++i) {
    const int row = rb + (i < 4 ? ty * 4 + i : 64 + ty * 4 + (i - 4));
    float4 o0, o1;
    o0.x = acc[i][0] + bl.x; o0.y = acc[i][1] + bl.y;
    o0.z = acc[i][2] + bl.z; o0.w = acc[i][3] + bl.w;
    o1.x = acc[i][4] + bh.x; o1.y = acc[i][5] + bh.y;
    o1.z = acc[i][6] + bh.z; o1.w = acc[i][7] + bh.w;
    *reinterpret_cast<float4*>(&C[(size_t)row * N + cb + tx * 4]) = o0;
    *reinterpret_cast<float4*>(&C[(size_t)row * N + cb + 64 + tx * 4]) = o1;
  }
}

// ---------------------------------------------------------------------------
// Attention v3: scores in SCALAR registers (float acc[2][8][4], all-static
// unrolled indexing, no references, no float4 persistent arrays — r4's float4
// score array was demoted to scratch: 18 GB HBM traffic, 6x regression).
// 34.8 KB LDS; __launch_bounds__(256,3) caps VGPR ~170 to guard vs spill.
// XCD swizzle: 16 q-tiles of one (b,h) land on one XCD (K/V L2 reuse).
// mask is int32 on device.
// ---------------------------------------------------------------------------
#define KLD 68   // padded LDS stride for K/V chunk (floats)

__global__ __launch_bounds__(256, 3) void attn_kernel(
    const float* __restrict__ Qg, const float* __restrict__ Kg,
    const float* __restrict__ Vg, const int* __restrict__ mask,
    float* __restrict__ e_out, float* __restrict__ attn_out) {
  const int lin = blockIdx.x;                  // 0..4095
  const int virt = (lin & 7) * 512 + (lin >> 3);
  const int qt = virt & 15;
  const int h  = (virt >> 4) & 15;
  const int b  = virt >> 8;
  const int q0 = qt * 32;

  __shared__ float Qs[64][34];    // [d][q] transposed Q tile (8.5 KB)
  __shared__ float KVs[64][KLD];  // QK: [d][k] chunk; PV: [k][d] chunk (17 KB)
  __shared__ float es[32][KLD];   // per-chunk normalized e (8.5 KB)

  const int tid = threadIdx.x;
  const int ty = tid >> 4, tx = tid & 15;

  // stage Q tile transposed -> Qs[d][q]
  #pragma unroll
  for (int i = 0; i < 2; ++i) {
    const int L = tid + i * 256;   // 512 float4
    const int q = L >> 4;
    const int dc = L & 15;
    const float4 v = *reinterpret_cast<const float4*>(
        &Qg[(size_t)(b * NE_ + q0 + q) * HHD_ + h * HD_ + dc * 4]);
    Qs[dc * 4 + 0][q] = v.x; Qs[dc * 4 + 1][q] = v.y;
    Qs[dc * 4 + 2][q] = v.z; Qs[dc * 4 + 3][q] = v.w;
  }

  float acc[2][8][4];   // plain scalar array: promoted to 64 VGPRs
  #pragma unroll
  for (int i = 0; i < 2; ++i)
    #pragma unroll
    for (int kt = 0; kt < 8; ++kt)
      #pragma unroll
      for (int j = 0; j < 4; ++j) acc[i][kt][j] = 0.f;

  // ---- QK^T: 8 chunks of 64 k ----
  #pragma unroll
  for (int kt = 0; kt < 8; ++kt) {
    __syncthreads();
    #pragma unroll
    for (int i = 0; i < 4; ++i) {
      const int L = tid + i * 256;   // 1024 float4
      const int kl = L >> 4;
      const int dc = L & 15;
      const float4 v = *reinterpret_cast<const float4*>(
          &Kg[(size_t)(b * NE_ + kt * 64 + kl) * HHD_ + h * HD_ + dc * 4]);
      KVs[dc * 4 + 0][kl] = v.x; KVs[dc * 4 + 1][kl] = v.y;
      KVs[dc * 4 + 2][kl] = v.z; KVs[dc * 4 + 3][kl] = v.w;
    }
    __syncthreads();
    #pragma unroll
    for (int d = 0; d < 64; ++d) {
      const float2 qv = *reinterpret_cast<const float2*>(&Qs[d][ty * 2]);
      const float4 kv = *reinterpret_cast<const float4*>(&KVs[d][tx * 4]);
      acc[0][kt][0] += qv.x * kv.x; acc[0][kt][1] += qv.x * kv.y;
      acc[0][kt][2] += qv.x * kv.z; acc[0][kt][3] += qv.x * kv.w;
      acc[1][kt][0] += qv.y * kv.x; acc[1][kt][1] += qv.y * kv.y;
      acc[1][kt][2] += qv.y * kv.z; acc[1][kt][3] += qv.y * kv.w;
    }
  }

  // ---- mask + scale + softmax (shuffle over 16-lane tx-group) ----
  #pragma unroll
  for (int i = 0; i < 2; ++i) {
    float m = -INFINITY;
    #pragma unroll
    for (int kt = 0; kt < 8; ++kt) {
      const int4 mv = *reinterpret_cast<const int4*>(
          &mask[(size_t)(b * NE_ + q0 + ty * 2 + i) * NE_ + kt * 64 + tx * 4]);
      const float s0 = mv.x ? -INFINITY : acc[i][kt][0] * 0.125f;
      const float s1 = mv.y ? -INFINITY : acc[i][kt][1] * 0.125f;
      const float s2 = mv.z ? -INFINITY : acc[i][kt][2] * 0.125f;
      const float s3 = mv.w ? -INFINITY : acc[i][kt][3] * 0.125f;
      acc[i][kt][0] = s0; acc[i][kt][1] = s1;
      acc[i][kt][2] = s2; acc[i][kt][3] = s3;
      m = fmaxf(m, fmaxf(fmaxf(s0, s1), fmaxf(s2, s3)));
    }
    #pragma unroll
    for (int off = 8; off >= 1; off >>= 1) m = fmaxf(m, __shfl_xor(m, off));

    float sum = 0.f;
    #pragma unroll
    for (int kt = 0; kt < 8; ++kt) {
      const float e0 = __expf(acc[i][kt][0] - m);
      const float e1 = __expf(acc[i][kt][1] - m);
      const float e2 = __expf(acc[i][kt][2] - m);
      const float e3 = __expf(acc[i][kt][3] - m);
      acc[i][kt][0] = e0; acc[i][kt][1] = e1;
      acc[i][kt][2] = e2; acc[i][kt][3] = e3;
      sum += e0 + e1 + e2 + e3;
    }
    #pragma unroll
    for (int off = 8; off >= 1; off >>= 1) sum += __shfl_xor(sum, off);
    const float inv = 1.0f / sum;

    #pragma unroll
    for (int kt = 0; kt < 8; ++kt) {
      const float e0 = acc[i][kt][0] * inv;
      const float e1 = acc[i][kt][1] * inv;
      const float e2 = acc[i][kt][2] * inv;
      const float e3 = acc[i][kt][3] * inv;
      acc[i][kt][0] = e0; acc[i][kt][1] = e1;
      acc[i][kt][2] = e2; acc[i][kt][3] = e3;
      float4 ev; ev.x = e0; ev.y = e1; ev.z = e2; ev.w = e3;
      *reinterpret_cast<float4*>(
          &e_out[(size_t)((b * H_ + h) * NE_ + q0 + ty * 2 + i) * NE_ +
                 kt * 64 + tx * 4]) = ev;
    }
  }

  // ---- PV: per chunk, stage e (from regs) + V tile, accumulate out ----
  float o0[4] = {0.f, 0.f, 0.f, 0.f};
  float o1[4] = {0.f, 0.f, 0.f, 0.f};
  #pragma unroll
  for (int kt = 0; kt < 8; ++kt) {
    __syncthreads();
    {
      float4 t0; t0.x = acc[0][kt][0]; t0.y = acc[0][kt][1];
      t0.z = acc[0][kt][2]; t0.w = acc[0][kt][3];
      *reinterpret_cast<float4*>(&es[ty * 2 + 0][tx * 4]) = t0;
      float4 t1; t1.x = acc[1][kt][0]; t1.y = acc[1][kt][1];
      t1.z = acc[1][kt][2]; t1.w = acc[1][kt][3];
      *reinterpret_cast<float4*>(&es[ty * 2 + 1][tx * 4]) = t1;
    }
    #pragma unroll
    for (int i = 0; i < 4; ++i) {
      const int L = tid + i * 256;
      const int kl = L >> 4;
      const int dc = L & 15;
      const float4 v = *reinterpret_cast<const float4*>(
          &Vg[(size_t)(b * NE_ + kt * 64 + kl) * HHD_ + h * HD_ + dc * 4]);
      *reinterpret_cast<float4*>(&KVs[kl][dc * 4]) = v;
    }
    __syncthreads();
    #pragma unroll
    for (int k2 = 0; k2 < 64; ++k2) {
      const float4 vv = *reinterpret_cast<const float4*>(&KVs[k2][tx * 4]);
      const float e0 = es[ty * 2 + 0][k2];
      const float e1 = es[ty * 2 + 1][k2];
      o0[0] += e0 * vv.x; o0[1] += e0 * vv.y;
      o0[2] += e0 * vv.z; o0[3] += e0 * vv.w;
      o1[0] += e1 * vv.x; o1[1] += e1 * vv.y;
      o1[2] += e1 * vv.z; o1[3] += e1 * vv.w;
    }
  }
  {
    float4 w0; w0.x = o0[0]; w0.y = o0[1]; w0.z = o0[2]; w0.w = o0[3];
    *reinterpret_cast<float4*>(
        &attn_out[(size_t)(b * NE_ + q0 + ty * 2 + 0) * HHD_ + h * HD_ +
                  tx * 4]) = w0;
    float4 w1; w1.x = o1[0]; w1.y = o1[1]; w1.z = o1[2]; w1.w = o1[3];
    *reinterpret_cast<float4*>(
        &attn_out[(size_t)(b * NE_ + q0 + ty * 2 + 1) * HHD_ + h * HD_ +
                  tx * 4]) = w1;
  }
}

// ---------------------------------------------------------------------------
extern "C" void kernel_launch(void* const* d_in, const int* in_sizes, int n_in,
                              void* d_out, int out_size, void* d_ws, size_t ws_size,
                              hipStream_t stream) {
  const float* events = (const float*)d_in[0];
  const int* mask = (const int*)d_in[1];            // bool -> int32 on device
  const float* n1a = (const float*)d_in[2];
  const float* n1b = (const float*)d_in[3];
  const float* WQw = (const float*)d_in[4];
  const float* WQb = (const float*)d_in[5];
  const float* WKw = (const float*)d_in[6];
  const float* WKb = (const float*)d_in[7];
  const float* WVw = (const float*)d_in[8];
  const float* WVb = (const float*)d_in[9];
  const float* WOw = (const float*)d_in[10];
  const float* WOb = (const float*)d_in[11];
  const float* n2a = (const float*)d_in[12];
  const float* n2b = (const float*)d_in[13];

  float* out = (float*)d_out;                       // [16,512,1024]
  float* e_out = out + (size_t)ROWS_ * NOUT_;       // [16,16,512,512]

  const size_t MAT = (size_t)ROWS_ * HHD_;          // 8M floats = 32 MB
  float* xn = (float*)d_ws;        // x_norm, later reused as attn concat out
  float* Qb = xn + MAT;            // Q, later reused as WO output
  float* Kb = Qb + MAT;
  float* Vb = Kb + MAT;
  float* attn = xn;
  float* wo_out = Qb;

  // 1) layernorm1
  layernorm_kernel<<<ROWS_, 256, 0, stream>>>(events, n1a, n1b, xn);

  // 2) Q/K/V projections
  dim3 gg(HHD_ / BT, ROWS_ / BT);  // (8, 64)
  gemm_nt_bias<<<gg, 256, 0, stream>>>(xn, WQw, WQb, Qb);
  gemm_nt_bias<<<gg, 256, 0, stream>>>(xn, WKw, WKb, Kb);
  gemm_nt_bias<<<gg, 256, 0, stream>>>(xn, WVw, WVb, Vb);

  // 3) attention (+ e output), XCD-swizzled 1-D grid
  attn_kernel<<<B_ * H_ * (NE_ / 32), 256, 0, stream>>>(Qb, Kb, Vb, mask,
                                                        e_out, attn);

  // 4) output projection
  gemm_nt_bias<<<gg, 256, 0, stream>>>(attn, WOw, WOb, wo_out);

  // 5) layernorm2
  layernorm_kernel<<<ROWS_, 256, 0, stream>>>(wo_out, n2a, n2b, out);
}

// Round 6
// 1793.827 us; speedup vs baseline: 4.8179x; 4.1779x over previous
//
#include <hip/hip_runtime.h>
#include <hip/hip_bf16.h>
#include <math.h>

// Problem constants
#define B_  16
#define NE_ 512
#define NIN_ 1024
#define NOUT_ 1024
#define H_ 16
#define HD_ 64
#define ROWS_ (B_ * NE_)          // 8192
#define HHD_ (H_ * HD_)           // 1024

// ---------------------------------------------------------------------------
// LayerNorm (PyTorch-style: unbiased std (ddof=1), eps added to std)
// ---------------------------------------------------------------------------
__global__ __launch_bounds__(256) void layernorm_kernel(
    const float* __restrict__ in, const float* __restrict__ alpha,
    const float* __restrict__ beta, float* __restrict__ out) {
  const int row = blockIdx.x;
  const int t = threadIdx.x;
  const float4 v = *reinterpret_cast<const float4*>(&in[(size_t)row * 1024 + t * 4]);
  float s = v.x + v.y + v.z + v.w;
  float ss = v.x * v.x + v.y * v.y + v.z * v.z + v.w * v.w;
  #pragma unroll
  for (int off = 32; off >= 1; off >>= 1) {
    s += __shfl_xor(s, off);
    ss += __shfl_xor(ss, off);
  }
  __shared__ float red[8];
  const int w = t >> 6, lane = t & 63;
  if (lane == 0) { red[w] = s; red[4 + w] = ss; }
  __syncthreads();
  s = red[0] + red[1] + red[2] + red[3];
  ss = red[4] + red[5] + red[6] + red[7];
  const float mean = s * (1.0f / 1024.0f);
  float var = (ss - 1024.0f * mean * mean) * (1.0f / 1023.0f);
  var = fmaxf(var, 0.0f);
  const float inv = 1.0f / (sqrtf(var) + 1e-6f);
  const float4 a = *reinterpret_cast<const float4*>(&alpha[t * 4]);
  const float4 bt = *reinterpret_cast<const float4*>(&beta[t * 4]);
  float4 o;
  o.x = a.x * (v.x - mean) * inv + bt.x;
  o.y = a.y * (v.y - mean) * inv + bt.y;
  o.z = a.z * (v.z - mean) * inv + bt.z;
  o.w = a.w * (v.w - mean) * inv + bt.w;
  *reinterpret_cast<float4*>(&out[(size_t)row * 1024 + t * 4]) = o;
}

// ---------------------------------------------------------------------------
// fp32 NT GEMM: C[M,N] = A[M,K] * W[N,K]^T + bias[N]  (unchanged, proven)
// ---------------------------------------------------------------------------
#define BT 128   // tile
#define BKK 16   // k-step
#define LDT 132  // padded LDS stride (floats)

__global__ __launch_bounds__(256) void gemm_nt_bias(
    const float* __restrict__ A, const float* __restrict__ W,
    const float* __restrict__ bias, float* __restrict__ C) {
  __shared__ float As[BKK][LDT];
  __shared__ float Ws[BKK][LDT];
  const int tid = threadIdx.x;
  const int ty = tid >> 4;   // 0..15
  const int tx = tid & 15;   // 0..15
  const int rb = blockIdx.y * BT;
  const int cb = blockIdx.x * BT;
  const int K = 1024, N = 1024;

  float acc[8][8] = {};

  for (int kt = 0; kt < K; kt += BKK) {
    #pragma unroll
    for (int i = 0; i < 2; ++i) {
      const int L = tid + i * 256;
      const int row = L >> 2;
      const int c4 = L & 3;
      const float4 av = *reinterpret_cast<const float4*>(
          &A[(size_t)(rb + row) * K + kt + c4 * 4]);
      As[c4 * 4 + 0][row] = av.x; As[c4 * 4 + 1][row] = av.y;
      As[c4 * 4 + 2][row] = av.z; As[c4 * 4 + 3][row] = av.w;
      const float4 wv = *reinterpret_cast<const float4*>(
          &W[(size_t)(cb + row) * K + kt + c4 * 4]);
      Ws[c4 * 4 + 0][row] = wv.x; Ws[c4 * 4 + 1][row] = wv.y;
      Ws[c4 * 4 + 2][row] = wv.z; Ws[c4 * 4 + 3][row] = wv.w;
    }
    __syncthreads();
    #pragma unroll
    for (int k = 0; k < BKK; ++k) {
      float ar[8], br[8];
      *reinterpret_cast<float4*>(&ar[0]) =
          *reinterpret_cast<const float4*>(&As[k][ty * 4]);
      *reinterpret_cast<float4*>(&ar[4]) =
          *reinterpret_cast<const float4*>(&As[k][64 + ty * 4]);
      *reinterpret_cast<float4*>(&br[0]) =
          *reinterpret_cast<const float4*>(&Ws[k][tx * 4]);
      *reinterpret_cast<float4*>(&br[4]) =
          *reinterpret_cast<const float4*>(&Ws[k][64 + tx * 4]);
      #pragma unroll
      for (int i = 0; i < 8; ++i)
        #pragma unroll
        for (int j = 0; j < 8; ++j)
          acc[i][j] += ar[i] * br[j];
    }
    __syncthreads();
  }

  const float4 bl = *reinterpret_cast<const float4*>(&bias[cb + tx * 4]);
  const float4 bh = *reinterpret_cast<const float4*>(&bias[cb + 64 + tx * 4]);
  #pragma unroll
  for (int i = 0; i < 8; ++i) {
    const int row = rb + (i < 4 ? ty * 4 + i : 64 + ty * 4 + (i - 4));
    float4 o0, o1;
    o0.x = acc[i][0] + bl.x; o0.y = acc[i][1] + bl.y;
    o0.z = acc[i][2] + bl.z; o0.w = acc[i][3] + bl.w;
    o1.x = acc[i][4] + bh.x; o1.y = acc[i][5] + bh.y;
    o1.z = acc[i][6] + bh.z; o1.w = acc[i][7] + bh.w;
    *reinterpret_cast<float4*>(&C[(size_t)row * N + cb + tx * 4]) = o0;
    *reinterpret_cast<float4*>(&C[(size_t)row * N + cb + 64 + tx * 4]) = o1;
  }
}

// ---------------------------------------------------------------------------
// Attention v4 — three-kernel split. Scores stage through e_out (a required
// output), so NO persistent per-thread score array exists anywhere (r4/r5's
// scratch catastrophes: 18-21 GB HBM traffic from compiler-demoted arrays).
// ---------------------------------------------------------------------------
#define ALD 68   // padded LDS stride (floats) for 64-wide tiles

// S[bh, q, k] = (Q[bh,q,:] . K[bh,k,:]) / 8, masked -> e_out (raw scores).
// 64x64 output tile per block, K-dim = 64 (one shot), acc[4][4] micro-tile.
__global__ __launch_bounds__(256) void qk_kernel(
    const float* __restrict__ Qg, const float* __restrict__ Kg,
    const int* __restrict__ mask, float* __restrict__ e_out) {
  const int kt = blockIdx.x;        // 0..7
  const int qt = blockIdx.y;        // 0..7
  const int bh = blockIdx.z;        // 0..255
  const int b = bh >> 4, h = bh & 15;
  const int q0 = qt * 64, k0 = kt * 64;

  __shared__ float Qs[64][ALD];  // [d][q]
  __shared__ float Ks[64][ALD];  // [d][k]

  const int tid = threadIdx.x;
  const int ty = tid >> 4, tx = tid & 15;

  #pragma unroll
  for (int i = 0; i < 4; ++i) {
    const int L = tid + i * 256;   // 1024 float4
    const int row = L >> 4;        // 0..63
    const int dc = L & 15;
    const float4 qv = *reinterpret_cast<const float4*>(
        &Qg[(size_t)(b * NE_ + q0 + row) * HHD_ + h * HD_ + dc * 4]);
    Qs[dc * 4 + 0][row] = qv.x; Qs[dc * 4 + 1][row] = qv.y;
    Qs[dc * 4 + 2][row] = qv.z; Qs[dc * 4 + 3][row] = qv.w;
    const float4 kv = *reinterpret_cast<const float4*>(
        &Kg[(size_t)(b * NE_ + k0 + row) * HHD_ + h * HD_ + dc * 4]);
    Ks[dc * 4 + 0][row] = kv.x; Ks[dc * 4 + 1][row] = kv.y;
    Ks[dc * 4 + 2][row] = kv.z; Ks[dc * 4 + 3][row] = kv.w;
  }
  __syncthreads();

  float acc[4][4] = {};
  #pragma unroll
  for (int d = 0; d < 64; ++d) {
    float ar[4], br[4];
    *reinterpret_cast<float4*>(&ar[0]) =
        *reinterpret_cast<const float4*>(&Qs[d][ty * 4]);
    *reinterpret_cast<float4*>(&br[0]) =
        *reinterpret_cast<const float4*>(&Ks[d][tx * 4]);
    #pragma unroll
    for (int i = 0; i < 4; ++i)
      #pragma unroll
      for (int j = 0; j < 4; ++j)
        acc[i][j] += ar[i] * br[j];
  }

  #pragma unroll
  for (int i = 0; i < 4; ++i) {
    const int q = q0 + ty * 4 + i;
    const int4 mv = *reinterpret_cast<const int4*>(
        &mask[(size_t)(b * NE_ + q) * NE_ + k0 + tx * 4]);
    float4 o;
    o.x = mv.x ? -INFINITY : acc[i][0] * 0.125f;
    o.y = mv.y ? -INFINITY : acc[i][1] * 0.125f;
    o.z = mv.z ? -INFINITY : acc[i][2] * 0.125f;
    o.w = mv.w ? -INFINITY : acc[i][3] * 0.125f;
    *reinterpret_cast<float4*>(
        &e_out[(size_t)(bh * NE_ + q) * NE_ + k0 + tx * 4]) = o;
  }
}

// In-place row softmax on e_out: one wave per 512-float row.
__global__ __launch_bounds__(256) void softmax_kernel(float* __restrict__ e) {
  const int w = threadIdx.x >> 6, lane = threadIdx.x & 63;
  const size_t row = (size_t)blockIdx.x * 4 + w;
  float* p = e + row * NE_;
  float4 v0 = *reinterpret_cast<const float4*>(&p[lane * 4]);
  float4 v1 = *reinterpret_cast<const float4*>(&p[256 + lane * 4]);
  float m = fmaxf(fmaxf(fmaxf(v0.x, v0.y), fmaxf(v0.z, v0.w)),
                  fmaxf(fmaxf(v1.x, v1.y), fmaxf(v1.z, v1.w)));
  #pragma unroll
  for (int off = 32; off >= 1; off >>= 1) m = fmaxf(m, __shfl_xor(m, off));
  v0.x = __expf(v0.x - m); v0.y = __expf(v0.y - m);
  v0.z = __expf(v0.z - m); v0.w = __expf(v0.w - m);
  v1.x = __expf(v1.x - m); v1.y = __expf(v1.y - m);
  v1.z = __expf(v1.z - m); v1.w = __expf(v1.w - m);
  float s = v0.x + v0.y + v0.z + v0.w + v1.x + v1.y + v1.z + v1.w;
  #pragma unroll
  for (int off = 32; off >= 1; off >>= 1) s += __shfl_xor(s, off);
  const float inv = 1.0f / s;
  v0.x *= inv; v0.y *= inv; v0.z *= inv; v0.w *= inv;
  v1.x *= inv; v1.y *= inv; v1.z *= inv; v1.w *= inv;
  *reinterpret_cast<float4*>(&p[lane * 4]) = v0;
  *reinterpret_cast<float4*>(&p[256 + lane * 4]) = v1;
}

// attn[b, q, h*64+d] = sum_k e[bh, q, k] * V[b, k, h*64+d]
// 64(q) x 64(d) tile per block, k-loop in chunks of 64, acc[4][4].
__global__ __launch_bounds__(256) void pv_kernel(
    const float* __restrict__ e, const float* __restrict__ Vg,
    float* __restrict__ attn_out) {
  const int qt = blockIdx.x;        // 0..7
  const int bh = blockIdx.y;        // 0..255
  const int b = bh >> 4, h = bh & 15;
  const int q0 = qt * 64;

  __shared__ float Es[64][ALD];  // [k][q]
  __shared__ float Vs[64][ALD];  // [k][d]

  const int tid = threadIdx.x;
  const int ty = tid >> 4, tx = tid & 15;

  float acc[4][4] = {};

  for (int kt = 0; kt < 8; ++kt) {
    __syncthreads();
    #pragma unroll
    for (int i = 0; i < 4; ++i) {
      const int L = tid + i * 256;   // 1024 float4
      const int row = L >> 4;        // 0..63
      const int dc = L & 15;
      const float4 ev = *reinterpret_cast<const float4*>(
          &e[(size_t)(bh * NE_ + q0 + row) * NE_ + kt * 64 + dc * 4]);
      Es[dc * 4 + 0][row] = ev.x; Es[dc * 4 + 1][row] = ev.y;
      Es[dc * 4 + 2][row] = ev.z; Es[dc * 4 + 3][row] = ev.w;
      const float4 vv = *reinterpret_cast<const float4*>(
          &Vg[(size_t)(b * NE_ + kt * 64 + row) * HHD_ + h * HD_ + dc * 4]);
      *reinterpret_cast<float4*>(&Vs[row][dc * 4]) = vv;
    }
    __syncthreads();
    #pragma unroll
    for (int k2 = 0; k2 < 64; ++k2) {
      float ar[4], br[4];
      *reinterpret_cast<float4*>(&ar[0]) =
          *reinterpret_cast<const float4*>(&Es[k2][ty * 4]);
      *reinterpret_cast<float4*>(&br[0]) =
          *reinterpret_cast<const float4*>(&Vs[k2][tx * 4]);
      #pragma unroll
      for (int i = 0; i < 4; ++i)
        #pragma unroll
        for (int j = 0; j < 4; ++j)
          acc[i][j] += ar[i] * br[j];
    }
  }

  #pragma unroll
  for (int i = 0; i < 4; ++i) {
    float4 o;
    o.x = acc[i][0]; o.y = acc[i][1]; o.z = acc[i][2]; o.w = acc[i][3];
    *reinterpret_cast<float4*>(
        &attn_out[(size_t)(b * NE_ + q0 + ty * 4 + i) * HHD_ + h * HD_ +
                  tx * 4]) = o;
  }
}

// ---------------------------------------------------------------------------
extern "C" void kernel_launch(void* const* d_in, const int* in_sizes, int n_in,
                              void* d_out, int out_size, void* d_ws, size_t ws_size,
                              hipStream_t stream) {
  const float* events = (const float*)d_in[0];
  const int* mask = (const int*)d_in[1];            // bool -> int32 on device
  const float* n1a = (const float*)d_in[2];
  const float* n1b = (const float*)d_in[3];
  const float* WQw = (const float*)d_in[4];
  const float* WQb = (const float*)d_in[5];
  const float* WKw = (const float*)d_in[6];
  const float* WKb = (const float*)d_in[7];
  const float* WVw = (const float*)d_in[8];
  const float* WVb = (const float*)d_in[9];
  const float* WOw = (const float*)d_in[10];
  const float* WOb = (const float*)d_in[11];
  const float* n2a = (const float*)d_in[12];
  const float* n2b = (const float*)d_in[13];

  float* out = (float*)d_out;                       // [16,512,1024]
  float* e_out = out + (size_t)ROWS_ * NOUT_;       // [16,16,512,512]

  const size_t MAT = (size_t)ROWS_ * HHD_;          // 8M floats = 32 MB
  float* xn = (float*)d_ws;        // x_norm, later reused as attn concat out
  float* Qb = xn + MAT;            // Q, later reused as WO output
  float* Kb = Qb + MAT;
  float* Vb = Kb + MAT;
  float* attn = xn;
  float* wo_out = Qb;

  // 1) layernorm1
  layernorm_kernel<<<ROWS_, 256, 0, stream>>>(events, n1a, n1b, xn);

  // 2) Q/K/V projections
  dim3 gg(HHD_ / BT, ROWS_ / BT);  // (8, 64)
  gemm_nt_bias<<<gg, 256, 0, stream>>>(xn, WQw, WQb, Qb);
  gemm_nt_bias<<<gg, 256, 0, stream>>>(xn, WKw, WKb, Kb);
  gemm_nt_bias<<<gg, 256, 0, stream>>>(xn, WVw, WVb, Vb);

  // 3) attention: QK^T -> e_out (raw), softmax in-place, PV
  qk_kernel<<<dim3(8, 8, 256), 256, 0, stream>>>(Qb, Kb, mask, e_out);
  softmax_kernel<<<(B_ * H_ * NE_) / 4, 256, 0, stream>>>(e_out);
  pv_kernel<<<dim3(8, 256), 256, 0, stream>>>(e_out, Vb, attn);

  // 4) output projection
  gemm_nt_bias<<<gg, 256, 0, stream>>>(attn, WOw, WOb, wo_out);

  // 5) layernorm2
  layernorm_kernel<<<ROWS_, 256, 0, stream>>>(wo_out, n2a, n2b, out);
}